// Round 5
// baseline (882.216 us; speedup 1.0000x reference)
//
#include <hip/hip_runtime.h>
#include <hip/hip_bf16.h>

// Problem: B=8192 rows, D=4096. 3 layers of relu(l2norm(h) @ W^T + b).
// GEMM: 256x256 tile, BK=64, 8 waves, 128 KiB LDS double-buffer, 4 phases
// per K-tile, counted vmcnt(4), 1 barrier/phase, setprio, XOR-swizzled LDS.
// ROUND 5: MFMA shape 16x16x32 -> 32x32x16 (measured 2495 vs 2075 TF, and
// halves MFMA instruction count). Same per-lane fragment size (bf16x8) ->
// staging, LDS layout/swizzle, vmcnt ledger, WAR proofs all unchanged.
// Phase p now computes K-step p (K=16) over the whole per-wave 128x64 out:
// acc[4 rowblk][2 colblk] f32x16, 8 MFMA/phase. bF (2x4 frags) read fully
// in ph0 pre-barrier (keeps "B(t) consumed at ph0 lgkm0" -> B(t+2) stage
// at ph2 legal). aS window-prefetch alternates sets as in round 4.

#define NROWS 8192
#define DIM   4096

typedef __bf16 bf16x8 __attribute__((ext_vector_type(8)));
typedef float  f32x16 __attribute__((ext_vector_type(16)));

__device__ static inline short f2bf(float f) {
  __hip_bfloat16 h = __float2bfloat16(f);
  return __builtin_bit_cast(short, h);
}

// raw barrier: compiler fence + s_barrier, NO vmcnt/lgkmcnt drain
#define BARRIER() do { asm volatile("" ::: "memory"); \
                       __builtin_amdgcn_s_barrier();  \
                       asm volatile("" ::: "memory"); } while (0)
#define LGKM0()  asm volatile("s_waitcnt lgkmcnt(0)" ::: "memory")

// ---------------------------------------------------------------------------
// C[M,N] = relu(A[M,K](bf16) . Bw[N,K](bf16)^T + bias[N]), fp32 out.
// 8 waves in 2(M)x4(N); per-wave out 128x64 = acc[4][2] 32x32 frags.
//
// Steady-state tile t (buf = t&1), ONE barrier per phase, phase = K-step:
//  ph0: stage A(t+1).h0 | bF[0..1][k0..3] (8 rd) | BAR | lgkm0 |
//       window aS1<-At ks1 | MFMA8(ks0, aS0)
//  ph1: stage A(t+1).h1 | BAR | lgkm0 | window aS0<-At ks2 | MFMA8(ks1, aS1)
//  ph2: stage B(t+2).h0 | pre-read aS1<-At ks3 | BAR | lgkm0 | MFMA8(ks2, aS0)
//  ph3: stage B(t+2).h1 | vmcnt(4) | BAR | lgkm0 |
//       window aS0<-A(t+1) ks0 | MFMA8(ks3, aS1)
// vmcnt ledger: enter t with [B(t+1)x4]; +A(t+1)x4, +B(t+2)x4 -> 12;
// vmcnt(4) retires B(t+1),A(t+1); exit [B(t+2)x4]. Tail t>=NT-2: vmcnt(0).
// WAR rule: a stage issued after BAR(q) is safe vs reads whose lgkm-wait
// precedes BAR(q) in program order -- all pairs verified (as round 4).
// ---------------------------------------------------------------------------
__global__ __launch_bounds__(512, 2)
void gemm256_bias_relu(const short* __restrict__ A,
                       const short* __restrict__ Bw,
                       const float* __restrict__ bias,
                       float* __restrict__ C,
                       int M, int N, int K)
{
  __shared__ short lds[4][16384];   // [buf*2+op][256 rows * 64 bf16] = 128 KiB

  // XCD-aware swizzle (bijective: grid % 8 == 0 here)
  int bid = blockIdx.x;
  const int nwg = gridDim.x;
  if ((nwg & 7) == 0) { const int cpx = nwg >> 3; bid = (bid & 7) * cpx + (bid >> 3); }
  const int nbn  = N >> 8;
  const int brow = (bid / nbn) << 8;
  const int bcol = (bid % nbn) << 8;

  const int lane = threadIdx.x & 63;
  const int wid  = threadIdx.x >> 6;   // 0..7
  const int wr   = wid >> 2;           // 0..1 : 128-row output band
  const int wc   = wid & 3;            // 0..3 : 64-col output band

  const int l31 = lane & 31;
  const int khi = lane >> 5;           // k-group within fragment

  float bv[2];
#pragma unroll
  for (int jb = 0; jb < 2; ++jb)
    bv[jb] = bias[bcol + wc * 64 + jb * 32 + l31];

  f32x16 acc[4][2] = {};

  const size_t Kz   = (size_t)K;
  const size_t rowK = Kz * 2;          // bytes per global row
  char* const  ldsB = (char*)&lds[0][0];

  // ---- staging addressing (coalesced, source pre-swizzled, hoisted) ----
  const int r8  = lane >> 3;
  const int kcs = (lane & 7) ^ r8;
  const char* AgL = (const char*)A  + (size_t)(brow + r8) * rowK + (size_t)kcs * 16;
  const char* BgL = (const char*)Bw + (size_t)(bcol + r8) * rowK + (size_t)kcs * 16;
  size_t rbo[4];                       // (wid*8 + {0,64,128,192}) * rowK
  int    rbb[4];                       // same, in LDS bytes (row*128)
#pragma unroll
  for (int i = 0; i < 4; ++i) {
    const int rb = wid * 8 + i * 64;
    rbo[i] = (size_t)rb * rowK;
    rbb[i] = rb * 128;
  }

  // stage one 128-row half: 2 x global_load_lds(16B) per thread
  auto stage_half = [&](int parity, int op, int h, int tile) {
    const char* gp = (op ? BgL : AgL) + ((size_t)tile << 7);
    char* lb = ldsB + (parity * 2 + op) * 32768;
#pragma unroll
    for (int s = 0; s < 2; ++s) {
      const int idx = h * 2 + s;
      __builtin_amdgcn_global_load_lds(
          (const __attribute__((address_space(1))) void*)(gp + rbo[idx]),
          (__attribute__((address_space(3))) void*)(lb + rbb[idx]), 16, 0, 0);
    }
  };

  // ---- fragment read addressing (swizzled: phys kc = kc ^ (row&7)) ----
  // 32x32x16 A/B operand: lane holds row l31, k = khi*8 + e (8 consecutive).
  // logical kc = kstep*2 + khi; row&7 == lane&7.
  int xoff[4];
#pragma unroll
  for (int k = 0; k < 4; ++k)
    xoff[k] = ((k * 2 + khi) ^ (lane & 7)) * 16;
  int arow[4], brw[2];
#pragma unroll
  for (int mb = 0; mb < 4; ++mb) arow[mb] = (wr * 128 + mb * 32 + l31) * 128;
#pragma unroll
  for (int jb = 0; jb < 2; ++jb) brw[jb] = (wc * 64 + jb * 32 + l31) * 128;

  const int NT = K >> 6;

  bf16x8 aS[2][4];   // [set][rowblk] -- sets alternate per phase
  bf16x8 bF[2][4];   // [colblk][kstep]

#define LOAD_A(SET, KS, PTR)                                                 \
  _Pragma("unroll")                                                          \
  for (int mb = 0; mb < 4; ++mb)                                             \
    aS[SET][mb] = *reinterpret_cast<const bf16x8*>((PTR) + arow[mb] + xoff[KS]);

#define MFMA8(KS, SET)                                                       \
  _Pragma("unroll")                                                          \
  for (int mb = 0; mb < 4; ++mb)                                             \
    _Pragma("unroll")                                                        \
    for (int jb = 0; jb < 2; ++jb)                                           \
      acc[mb][jb] = __builtin_amdgcn_mfma_f32_32x32x16_bf16(                 \
          aS[SET][mb], bF[jb][KS], acc[mb][jb], 0, 0, 0);

  // ---- prologue: A0, B0, B1 (12 loads); land A0,B0; publish; pre-read aS0
  stage_half(0, 0, 0, 0); stage_half(0, 0, 1, 0);
  stage_half(0, 1, 0, 0); stage_half(0, 1, 1, 0);
  if (NT > 1) { stage_half(1, 1, 0, 1); stage_half(1, 1, 1, 1); }
  if (NT > 1) asm volatile("s_waitcnt vmcnt(4)" ::: "memory");
  else        asm volatile("s_waitcnt vmcnt(0)" ::: "memory");
  BARRIER();
  {
    const char* A0 = ldsB;
    LOAD_A(0, 0, A0)
  }

  for (int t = 0; t < NT; ++t) {
    const int cur = t & 1, nxt = cur ^ 1;
    const char* At = ldsB + (cur * 2 + 0) * 32768;
    const char* Bt = ldsB + (cur * 2 + 1) * 32768;
    const char* An = ldsB + (nxt * 2 + 0) * 32768;

    // ---- phase 0 (kstep 0): all bF reads; stage A(t+1).h0 ----
    if (t + 1 < NT) stage_half(nxt, 0, 0, t + 1);
#pragma unroll
    for (int jb = 0; jb < 2; ++jb)
#pragma unroll
      for (int k = 0; k < 4; ++k)
        bF[jb][k] = *reinterpret_cast<const bf16x8*>(Bt + brw[jb] + xoff[k]);
    BARRIER();
    LGKM0();
    LOAD_A(1, 1, At)
    __builtin_amdgcn_s_setprio(1);
    MFMA8(0, 0)
    __builtin_amdgcn_s_setprio(0);

    // ---- phase 1 (kstep 1) ----
    if (t + 1 < NT) stage_half(nxt, 0, 1, t + 1);
    BARRIER();
    LGKM0();
    LOAD_A(0, 2, At)
    __builtin_amdgcn_s_setprio(1);
    MFMA8(1, 1)
    __builtin_amdgcn_s_setprio(0);

    // ---- phase 2 (kstep 2): aS1 pre-read (lgkm'd at this phase's gate,
    //      safe vs next-tile ph0 A-stage per the BAR(q) rule) ----
    if (t + 2 < NT) stage_half(cur, 1, 0, t + 2);
    LOAD_A(1, 3, At)
    BARRIER();
    LGKM0();
    __builtin_amdgcn_s_setprio(1);
    MFMA8(2, 0)
    __builtin_amdgcn_s_setprio(0);

    // ---- phase 3 (kstep 3): counted vmcnt before barrier; window
    //      prefetches next tile's aS0 ----
    if (t + 2 < NT) stage_half(cur, 1, 1, t + 2);
    if (t >= NT - 2) asm volatile("s_waitcnt vmcnt(0)" ::: "memory");
    else             asm volatile("s_waitcnt vmcnt(4)" ::: "memory");
    BARRIER();
    LGKM0();
    if (t + 1 < NT) { LOAD_A(0, 0, An) }
    __builtin_amdgcn_s_setprio(1);
    MFMA8(3, 1)
    __builtin_amdgcn_s_setprio(0);
  }
#undef MFMA8
#undef LOAD_A

  // epilogue: 32x32 C/D layout: col = lane&31, row = (r&3)+8*(r>>2)+4*khi
#pragma unroll
  for (int mb = 0; mb < 4; ++mb) {
    const int rb0 = brow + wr * 128 + mb * 32 + 4 * khi;
#pragma unroll
    for (int jb = 0; jb < 2; ++jb) {
      const int col = bcol + wc * 64 + jb * 32 + l31;
#pragma unroll
      for (int r = 0; r < 16; ++r) {
        const int row = rb0 + (r & 3) + 8 * (r >> 2);
        const float v = acc[mb][jb][r] + bv[jb];
        C[(size_t)row * N + col] = v > 0.f ? v : 0.f;
      }
    }
  }
}

// ---------------------------------------------------------------------------
// Row L2-normalize (fp32 in) -> bf16 out. One block (256 thr) per row of 4096.
// ---------------------------------------------------------------------------
__global__ __launch_bounds__(256)
void rownorm_bf16(const float* __restrict__ in, short* __restrict__ out)
{
  const int row = blockIdx.x;
  const int t0  = threadIdx.x;
  const float4* inr = (const float4*)(in + (size_t)row * DIM);

  float4 v[4];
  float ss = 0.f;
#pragma unroll
  for (int t = 0; t < 4; ++t) {
    v[t] = inr[t0 + t * 256];
    ss += v[t].x * v[t].x + v[t].y * v[t].y + v[t].z * v[t].z + v[t].w * v[t].w;
  }
#pragma unroll
  for (int off = 32; off > 0; off >>= 1)
    ss += __shfl_down(ss, off, 64);

  __shared__ float wss[4];
  if ((t0 & 63) == 0) wss[t0 >> 6] = ss;
  __syncthreads();
  const float tot   = wss[0] + wss[1] + wss[2] + wss[3];
  const float scale = 1.f / fmaxf(sqrtf(tot), 1e-12f);  // F.normalize eps

  short4* outr = (short4*)(out + (size_t)row * DIM);
#pragma unroll
  for (int t = 0; t < 4; ++t) {
    short4 o;
    o.x = f2bf(v[t].x * scale);
    o.y = f2bf(v[t].y * scale);
    o.z = f2bf(v[t].z * scale);
    o.w = f2bf(v[t].w * scale);
    outr[t0 + t * 256] = o;
  }
}

// ---------------------------------------------------------------------------
// fp32 -> bf16 bulk cast (for W), vectorized, grid-stride.
// ---------------------------------------------------------------------------
__global__ __launch_bounds__(256)
void cast_bf16(const float* __restrict__ in, short* __restrict__ out, int n4)
{
  int i = blockIdx.x * 256 + threadIdx.x;
  const int stride = gridDim.x * 256;
  for (; i < n4; i += stride) {
    const float4 v = ((const float4*)in)[i];
    short4 o;
    o.x = f2bf(v.x);
    o.y = f2bf(v.y);
    o.z = f2bf(v.z);
    o.w = f2bf(v.w);
    ((short4*)out)[i] = o;
  }
}

extern "C" void kernel_launch(void* const* d_in, const int* in_sizes, int n_in,
                              void* d_out, int out_size, void* d_ws, size_t ws_size,
                              hipStream_t stream) {
  const float* x = (const float*)d_in[0];
  const float* W[3]    = { (const float*)d_in[1], (const float*)d_in[3], (const float*)d_in[5] };
  const float* bias[3] = { (const float*)d_in[2], (const float*)d_in[4], (const float*)d_in[6] };
  float* out = (float*)d_out;

  // workspace layout: hn bf16 [8192][4096] (64 MiB) | Wb bf16 [4096][4096] (32 MiB)
  short* hn = (short*)d_ws;
  short* Wb = (short*)((char*)d_ws + (size_t)NROWS * DIM * 2);

  const size_t layer_elems = (size_t)NROWS * DIM;
  const float* hin = x;

  for (int L = 0; L < 3; ++L) {
    cast_bf16<<<2048, 256, 0, stream>>>(W[L], Wb, DIM * DIM / 4);
    rownorm_bf16<<<NROWS, 256, 0, stream>>>(hin, hn);
    gemm256_bias_relu<<<(NROWS / 256) * (DIM / 256), 512, 0, stream>>>(
        hn, Wb, bias[L], out + (size_t)L * layer_elems, NROWS, DIM, DIM);
    hin = out + (size_t)L * layer_elems;
  }
}

// Round 6
// 779.087 us; speedup vs baseline: 1.1324x; 1.1324x over previous
//
#include <hip/hip_runtime.h>
#include <hip/hip_bf16.h>

// Problem: B=8192 rows, D=4096. 3 layers of relu(l2norm(h) @ W^T + b).
// GEMM: 256x256 tile, BK=64, 8 waves, 128 KiB LDS double-buffer, 16x16x32
// MFMA (reverted from 32x32x16: that shape bank-conflicted, 2.5e7 cycles).
// ROUND 6: 2 phases per K-tile (was 4). Rationale: OccupancyPercent shows
// 1 block/CU (LDS-capped) -> every gate stall is pure idle; R4 proved
// residue ~ gate count. Full-tile fragments (aX,aY,bF = 96 VGPR) now fit
// because 2 waves/SIMD allows 256 combined regs. Uniform staging offsets
// forced to SGPR via readfirstlane.
//
// Steady-state tile t (buf = t&1):
//  ph0: stage A(t+1).h0+h1 (4 ld) | read bF(t) x8 | BAR | lgkm0+schedbar |
//       window: aY(t) x8 (rows 64..127) | MFMA32(acc[0..3], aX, bF)
//  ph1: vmcnt(0) [A(t+1),B(t+1) land; B(t+2) not yet issued] | BAR |
//       lgkm0+schedbar [aY done] | stage B(t+2).h0+h1 (4 ld) |
//       window: aX(t+1) x8 [A(t+1) published] | MFMA32(acc[4..7], aY, bF)
// WAR proofs (rule: stage only after a barrier that follows readers' lgkm0):
//  - B(t+2) (ph1, after BAR(ph0)): bF(t) readers gated at ph0 lgkm0 ✓
//  - A(t+1) (ph0 pre-BAR, after BAR(ph1,t-1)): aX/aY(t-1) gated at
//    ph0/ph1(t-1) lgkm0 ✓ (other buffer anyway for aX/aY(t))
//  - aX(t+1) window read vs A(t+3) stage (ph0,t+2, after BAR(ph1,t+1)
//    which follows ph0(t+1) lgkm0 = aX's gate) ✓
// vmcnt: entering t: {B(t+1)x4}; ph0 adds A(t+1)x4; ph1 vmcnt(0) drains
// both (issued >=1 phase ago, ~no stall); then B(t+2)x4 issued -> invariant.
// Register reuse: aX/aY/bF plain arrays -- each rewrite is after last use.

#define NROWS 8192
#define DIM   4096

typedef __bf16 bf16x8 __attribute__((ext_vector_type(8)));
typedef float  f32x4  __attribute__((ext_vector_type(4)));

__device__ static inline short f2bf(float f) {
  __hip_bfloat16 h = __float2bfloat16(f);
  return __builtin_bit_cast(short, h);
}

#define BARRIER() do { asm volatile("" ::: "memory"); \
                       __builtin_amdgcn_s_barrier();  \
                       asm volatile("" ::: "memory"); } while (0)
#define GATE()   do { asm volatile("s_waitcnt lgkmcnt(0)" ::: "memory"); \
                      __builtin_amdgcn_sched_barrier(0); } while (0)

__global__ __launch_bounds__(512, 2)
void gemm256_bias_relu(const short* __restrict__ A,
                       const short* __restrict__ Bw,
                       const float* __restrict__ bias,
                       float* __restrict__ C,
                       int M, int N, int K)
{
  __shared__ short lds[4][16384];   // [buf*2+op][256 rows * 64 bf16] = 128 KiB

  // XCD-aware swizzle (bijective: grid % 8 == 0 here)
  int bid = blockIdx.x;
  const int nwg = gridDim.x;
  if ((nwg & 7) == 0) { const int cpx = nwg >> 3; bid = (bid & 7) * cpx + (bid >> 3); }
  const int nbn  = N >> 8;
  const int brow = (bid / nbn) << 8;
  const int bcol = (bid % nbn) << 8;

  const int lane = threadIdx.x & 63;
  const int wid  = __builtin_amdgcn_readfirstlane(threadIdx.x >> 6);  // uniform
  const int wr   = wid >> 2;           // 0..1 : 128-row output band
  const int wc   = wid & 3;            // 0..3 : 64-col output band

  float bv[4];
#pragma unroll
  for (int j = 0; j < 4; ++j)
    bv[j] = bias[bcol + wc * 64 + j * 16 + (lane & 15)];

  f32x4 acc[8][4] = {};

  const size_t rowK = (size_t)K * 2;   // bytes per global row
  char* const  ldsB = (char*)&lds[0][0];

  // ---- staging addressing (coalesced, source pre-swizzled) ----
  const int r8  = lane >> 3;
  const int kcs = (lane & 7) ^ r8;
  const char* AgL = (const char*)A  + (size_t)(brow + r8) * rowK + (size_t)kcs * 16;
  const char* BgL = (const char*)Bw + (size_t)(bcol + r8) * rowK + (size_t)kcs * 16;
  int rbo[4], rbb[4];                  // wave-uniform (wid-derived) -> SGPR
#pragma unroll
  for (int i = 0; i < 4; ++i) {
    const int rb = wid * 8 + i * 64;
    rbo[i] = rb * (int)rowK;
    rbb[i] = rb * 128;
  }

  // stage one full tile operand half: 2 x global_load_lds(16B) per thread
  auto stage_half = [&](int parity, int op, int h, int tile) {
    const char* gp = (op ? BgL : AgL) + ((size_t)tile << 7);
    char* lb = ldsB + (parity * 2 + op) * 32768;
#pragma unroll
    for (int s = 0; s < 2; ++s) {
      const int idx = h * 2 + s;
      __builtin_amdgcn_global_load_lds(
          (const __attribute__((address_space(1))) void*)(gp + rbo[idx]),
          (__attribute__((address_space(3))) void*)(lb + rbb[idx]), 16, 0, 0);
    }
  };

  // ---- fragment read addressing (swizzled: phys kc = kc ^ (row&7)) ----
  const int l15  = lane & 15;
  const int xlo  = ((lane >> 4) ^ (lane & 3)) * 16;
  const int b2   = (lane >> 2) & 1;
  const int k64[2] = { b2 << 6, (1 - b2) << 6 };
  const int abase = (wr * 128 + l15) * 128 + xlo;
  const int bbase = (wc * 64  + l15) * 128 + xlo;

  const int NT = K >> 6;

  bf16x8 aX[4][2], aY[4][2], bF[4][2];   // plain arrays; rewrites follow last use

#define LOAD_FRAG(DST, PTR, BASE, I0)                                        \
  _Pragma("unroll")                                                          \
  for (int ii = 0; ii < 4; ++ii)                                             \
    _Pragma("unroll")                                                        \
    for (int ks = 0; ks < 2; ++ks)                                           \
      DST[ii][ks] = *reinterpret_cast<const bf16x8*>(                        \
          (PTR) + (BASE) + ((I0) + ii) * 2048 + k64[ks]);

// ks outer: same-acc revisit distance = 16 instructions
#define MFMA16(I0, AF)                                                       \
  _Pragma("unroll")                                                          \
  for (int ks = 0; ks < 2; ++ks)                                             \
    _Pragma("unroll")                                                        \
    for (int ii = 0; ii < 4; ++ii)                                           \
      _Pragma("unroll")                                                      \
      for (int j = 0; j < 4; ++j)                                            \
        acc[(I0) + ii][j] = __builtin_amdgcn_mfma_f32_16x16x32_bf16(         \
            AF[ii][ks], bF[j][ks], acc[(I0) + ii][j], 0, 0, 0);

  // ---- prologue: stage A0,B0,B1; land A0,B0 (vmcnt(4): B1 stays in
  //      flight); publish; pre-read aX(0) ----
  stage_half(0, 0, 0, 0); stage_half(0, 0, 1, 0);
  stage_half(0, 1, 0, 0); stage_half(0, 1, 1, 0);
  if (NT > 1) { stage_half(1, 1, 0, 1); stage_half(1, 1, 1, 1); }
  if (NT > 1) asm volatile("s_waitcnt vmcnt(4)" ::: "memory");
  else        asm volatile("s_waitcnt vmcnt(0)" ::: "memory");
  BARRIER();
  LOAD_FRAG(aX, ldsB, abase, 0)        // drains at ph0's gate

  for (int t = 0; t < NT; ++t) {
    const int cur = t & 1, nxt = cur ^ 1;
    const char* At = ldsB + (cur * 2 + 0) * 32768;
    const char* Bt = ldsB + (cur * 2 + 1) * 32768;
    const char* An = ldsB + (nxt * 2 + 0) * 32768;

    // ---- phase 0 ----
    if (t + 1 < NT) { stage_half(nxt, 0, 0, t + 1); stage_half(nxt, 0, 1, t + 1); }
    LOAD_FRAG(bF, Bt, bbase, 0)
    BARRIER();
    GATE();                              // bF + aX ready
    LOAD_FRAG(aY, At, abase, 4)          // overlaps MFMA below
    __builtin_amdgcn_s_setprio(1);
    MFMA16(0, aX)
    __builtin_amdgcn_s_setprio(0);

    // ---- phase 1 ----
    asm volatile("s_waitcnt vmcnt(0)" ::: "memory");  // A(t+1),B(t+1) land
    BARRIER();
    GATE();                              // aY ready
    if (t + 2 < NT) { stage_half(cur, 1, 0, t + 2); stage_half(cur, 1, 1, t + 2); }
    if (t + 1 < NT) { LOAD_FRAG(aX, An, abase, 0) }   // next tile's aX
    __builtin_amdgcn_s_setprio(1);
    MFMA16(4, aY)
    __builtin_amdgcn_s_setprio(0);
  }
#undef MFMA16
#undef LOAD_FRAG

  // epilogue: C/D layout col = lane&15, row = (lane>>4)*4 + reg
#pragma unroll
  for (int i = 0; i < 8; ++i) {
    const int rbase = brow + wr * 128 + i * 16 + ((lane >> 4) << 2);
#pragma unroll
    for (int j = 0; j < 4; ++j) {
      const int col = bcol + wc * 64 + j * 16 + (lane & 15);
#pragma unroll
      for (int r = 0; r < 4; ++r) {
        const float v = acc[i][j][r] + bv[j];
        C[(size_t)(rbase + r) * N + col] = v > 0.f ? v : 0.f;
      }
    }
  }
}

// ---------------------------------------------------------------------------
// Row L2-normalize (fp32 in) -> bf16 out. One block (256 thr) per row of 4096.
// ---------------------------------------------------------------------------
__global__ __launch_bounds__(256)
void rownorm_bf16(const float* __restrict__ in, short* __restrict__ out)
{
  const int row = blockIdx.x;
  const int t0  = threadIdx.x;
  const float4* inr = (const float4*)(in + (size_t)row * DIM);

  float4 v[4];
  float ss = 0.f;
#pragma unroll
  for (int t = 0; t < 4; ++t) {
    v[t] = inr[t0 + t * 256];
    ss += v[t].x * v[t].x + v[t].y * v[t].y + v[t].z * v[t].z + v[t].w * v[t].w;
  }
#pragma unroll
  for (int off = 32; off > 0; off >>= 1)
    ss += __shfl_down(ss, off, 64);

  __shared__ float wss[4];
  if ((t0 & 63) == 0) wss[t0 >> 6] = ss;
  __syncthreads();
  const float tot   = wss[0] + wss[1] + wss[2] + wss[3];
  const float scale = 1.f / fmaxf(sqrtf(tot), 1e-12f);  // F.normalize eps

  short4* outr = (short4*)(out + (size_t)row * DIM);
#pragma unroll
  for (int t = 0; t < 4; ++t) {
    short4 o;
    o.x = f2bf(v[t].x * scale);
    o.y = f2bf(v[t].y * scale);
    o.z = f2bf(v[t].z * scale);
    o.w = f2bf(v[t].w * scale);
    outr[t0 + t * 256] = o;
  }
}

// ---------------------------------------------------------------------------
// fp32 -> bf16 bulk cast (for W), vectorized, grid-stride.
// ---------------------------------------------------------------------------
__global__ __launch_bounds__(256)
void cast_bf16(const float* __restrict__ in, short* __restrict__ out, int n4)
{
  int i = blockIdx.x * 256 + threadIdx.x;
  const int stride = gridDim.x * 256;
  for (; i < n4; i += stride) {
    const float4 v = ((const float4*)in)[i];
    short4 o;
    o.x = f2bf(v.x);
    o.y = f2bf(v.y);
    o.z = f2bf(v.z);
    o.w = f2bf(v.w);
    ((short4*)out)[i] = o;
  }
}

extern "C" void kernel_launch(void* const* d_in, const int* in_sizes, int n_in,
                              void* d_out, int out_size, void* d_ws, size_t ws_size,
                              hipStream_t stream) {
  const float* x = (const float*)d_in[0];
  const float* W[3]    = { (const float*)d_in[1], (const float*)d_in[3], (const float*)d_in[5] };
  const float* bias[3] = { (const float*)d_in[2], (const float*)d_in[4], (const float*)d_in[6] };
  float* out = (float*)d_out;

  // workspace layout: hn bf16 [8192][4096] (64 MiB) | Wb bf16 [4096][4096] (32 MiB)
  short* hn = (short*)d_ws;
  short* Wb = (short*)((char*)d_ws + (size_t)NROWS * DIM * 2);

  const size_t layer_elems = (size_t)NROWS * DIM;
  const float* hin = x;

  for (int L = 0; L < 3; ++L) {
    cast_bf16<<<2048, 256, 0, stream>>>(W[L], Wb, DIM * DIM / 4);
    rownorm_bf16<<<NROWS, 256, 0, stream>>>(hin, hn);
    gemm256_bias_relu<<<(NROWS / 256) * (DIM / 256), 512, 0, stream>>>(
        hn, Wb, bias[L], out + (size_t)L * layer_elems, NROWS, DIM, DIM);
    hin = out + (size_t)L * layer_elems;
  }
}